// Round 3
// baseline (471.176 us; speedup 1.0000x reference)
//
#include <hip/hip_runtime.h>
#include <hip/hip_bf16.h>

// CapsuleLayerWithRouting: batch=128, in_caps=1152, in_hid=16, out_caps=32,
// out_hid=16, 3 routing iterations (fixed). fp32 in/out.
//
// Round-8: single cooperative kernel with HAND-ROLLED grid barriers.
// Evidence: r6 proved coop launch works here but cg::grid.sync() ~50us/sync;
// r7 showed the 7-kernel path spends ~25+us in gaps/ramps. This round fuses
// all phases into one kernel with a counter barrier (release atomicAdd +
// relaxed-poll + s_sleep(1) + acquire fence): 6 barriers @ ~1-3us replace
// 6 gaps @ ~4-6us + 2 redundant build_xs + cold Wb re-reads.
//  - conv phase XCD-aligned: Wb[iblk] written by blocks with bid%8==iblk%8,
//    consumed by the same blocks' pass phases -> Wb lives in local L2.
//  - xs (X fragments) built ONCE, persists in LDS across all 3 passes.
//  - LDS union: conv st[16][516] (33KB) = xs(18K)+part(2K)+red(8K).
//  - ctr zeroed via hipMemsetAsync each call (workspace is re-poisoned).
//  - fallback: verified round-7 7-kernel path if coop launch is rejected.
// Fragment layouts (HW-verified m89/m91):
//   A[m=lane&15][k=(lane>>4)*8+j]  B[k=(lane>>4)*8+j][n=lane&15]
//   D[row=(lane>>4)*4+reg][col=lane&15]

#define IN_CAPS 1152
#define OUT_CAPS 32
#define BATCH 128
#define IPC 18
#define NBLK_I (IN_CAPS / IPC)               // 64
#define SV_ELEMS (BATCH * OUT_CAPS * 16)     // 65536
#define GRID 512

typedef __attribute__((ext_vector_type(8))) short short8;
typedef __attribute__((ext_vector_type(4))) float f32x4;

__device__ inline unsigned f2bf(float x) {          // RNE fp32 -> bf16
  unsigned u = __builtin_bit_cast(unsigned, x);
  return (u + 0x7FFFu + ((u >> 16) & 1u)) >> 16;
}

// ---- hand-rolled grid barrier: release-add, relaxed poll, acquire fence.
// Safe only under cooperative launch (all blocks resident). ----
__device__ __forceinline__ void grid_bar(unsigned* __restrict__ ctr,
                                         unsigned target, int t) {
  __syncthreads();                           // all lanes done with prior phase
  if (t == 0) {
    __hip_atomic_fetch_add(ctr, 1u, __ATOMIC_ACQ_REL, __HIP_MEMORY_SCOPE_AGENT);
    while (__hip_atomic_load(ctr, __ATOMIC_RELAXED, __HIP_MEMORY_SCOPE_AGENT) <
           target)
      __builtin_amdgcn_s_sleep(1);
    __threadfence();                         // acquire: invalidate stale caches
  }
  __syncthreads();                           // block resumes after thread-0
}

// ---- convert one i of W [16][512] fp32 -> A-fragments, 512 threads ----
__device__ __forceinline__ void conv_i(const float* __restrict__ W,
                                       unsigned short* __restrict__ Wb,
                                       float* st, int i, int t) {
  const float4* src = (const float4*)(W + (size_t)i * 8192);
  float4 g[4];
#pragma unroll
  for (int r = 0; r < 4; ++r) g[r] = src[r * 512 + t];
#pragma unroll
  for (int r = 0; r < 4; ++r) {
    const int f = r * 512 + t;                // 0..2047 float4s
    const int k = f >> 7, c4 = f & 127;
    *(float4*)&st[k * 516 + c4 * 4] = g[r];   // stride 516: 2-way banks only
  }
  __syncthreads();
  unsigned short* dst = Wb + (size_t)i * 8192;
#pragma unroll
  for (int r = 0; r < 2; ++r) {
    const int uu = r * 512 + t;               // 0..1023 = o*32 + l
    const int o = uu >> 5, ll = uu & 31;
    const int col = o * 16 + (ll & 15), k0 = (ll >> 4) * 8;
    unsigned b[8];
#pragma unroll
    for (int j = 0; j < 8; ++j) b[j] = f2bf(st[(k0 + j) * 516 + col]);
    uint4 outv;
    outv.x = b[0] | (b[1] << 16);
    outv.y = b[2] | (b[3] << 16);
    outv.z = b[4] | (b[5] << 16);
    outv.w = b[6] | (b[7] << 16);
    *(uint4*)(dst + (size_t)uu * 8) = outv;   // consecutive uu -> coalesced
  }
  __syncthreads();                            // st reused by next i / xs
}

// ---- build x B-fragment slice in LDS: xs[i][lane][4 uints] (16B/lane),
// zeros in lanes 32-63 (the k=16..31 zero pad) ----
__device__ __forceinline__ void build_xs(const float* __restrict__ X, int bg,
                                         int i0, int t, unsigned (*xs)[64][4]) {
#pragma unroll
  for (int rep = 0; rep < IPC * 256 / 512; ++rep) {
    const int base = rep * 512 + t;
    const int ii = base >> 8;
    const int e = base & 255;
    const int l2 = e >> 2, ju = e & 3;
    unsigned val = 0;
    if (l2 < 32) {
      const float2 f = *(const float2*)(X +
          ((size_t)(bg * 16 + (l2 & 15)) * IN_CAPS + (i0 + ii)) * 16 +
          (l2 >> 4) * 8 + 2 * ju);
      val = f2bf(f.x) | (f2bf(f.y) << 16);
    }
    xs[ii][l2][ju] = val;
  }
}

__device__ __forceinline__ short8 ld_x(const unsigned (*xs)[64][4], int ii, int l) {
  return __builtin_bit_cast(short8, *(const uint4*)(&xs[ii][l][0]));
}

// ---- pass 1 body: C = 1/32 uniform -> S1 partials ----
__device__ __forceinline__ void pass1_phase(const short8* __restrict__ wpb,
                                            const unsigned (*xs)[64][4],
                                            float* __restrict__ pp, int l) {
  const short8* wp = wpb;
  f32x4 sacc[4];
#pragma unroll
  for (int m = 0; m < 4; ++m) sacc[m] = (f32x4){0.f, 0.f, 0.f, 0.f};
  for (int ii = 0; ii < IPC; ++ii) {
    short8 x = ld_x(xs, ii, l);
    short8 a0 = wp[0], a1 = wp[32], a2 = wp[64], a3 = wp[96];
    wp += 1024;
    sacc[0] = __builtin_amdgcn_mfma_f32_16x16x32_bf16(a0, x, sacc[0], 0, 0, 0);
    sacc[1] = __builtin_amdgcn_mfma_f32_16x16x32_bf16(a1, x, sacc[1], 0, 0, 0);
    sacc[2] = __builtin_amdgcn_mfma_f32_16x16x32_bf16(a2, x, sacc[2], 0, 0, 0);
    sacc[3] = __builtin_amdgcn_mfma_f32_16x16x32_bf16(a3, x, sacc[3], 0, 0, 0);
  }
#pragma unroll
  for (int m = 0; m < 4; ++m) *(f32x4*)(pp + m * 16) = sacc[m] * (1.f / 32.f);
}

// ---- passes 2/3 body: dot = u.V; C = softmax(dot); S += C*u.
// Two routing-i per barrier; part[] is a 4-slot ring (WAR fenced). ----
__device__ __forceinline__ void pass23_phase(const short8* __restrict__ wpb,
                                             const unsigned (*xs)[64][4],
                                             float (*part)[8][16],
                                             const float* __restrict__ Vt,
                                             float* __restrict__ pp,
                                             int bg, int w, int l, int q, int bl) {
  f32x4 v[4], sacc[4];
#pragma unroll
  for (int m = 0; m < 4; ++m) {
    v[m] = ((const f32x4*)Vt)[((size_t)(bg * 8 + w) * 64 + l) * 4 + m];
    sacc[m] = (f32x4){0.f, 0.f, 0.f, 0.f};
  }

  const short8* wp = wpb;
  short8 an[4];
  short8 xn = ld_x(xs, 0, l);
#pragma unroll
  for (int m = 0; m < 4; ++m) an[m] = wp[m * 32];
  wp += 1024;

  for (int pr2 = 0; pr2 < IPC / 2; ++pr2) {
    f32x4 dk0[4], dk1[4];
    const int s0 = (pr2 & 1) * 2;            // part slot pair for this pr2
    {                                        // ---- half 0 (ii = 2*pr2) ----
      short8 ac[4];
      short8 xc = xn;
#pragma unroll
      for (int m = 0; m < 4; ++m) ac[m] = an[m];
      xn = ld_x(xs, 2 * pr2 + 1, l);         // always valid (<= 17)
#pragma unroll
      for (int m = 0; m < 4; ++m) an[m] = wp[m * 32];
      wp += 1024;
      const f32x4 z = {0.f, 0.f, 0.f, 0.f};
      f32x4 d[4];
      float e[4];
#pragma unroll
      for (int m = 0; m < 4; ++m)
        d[m] = __builtin_amdgcn_mfma_f32_16x16x32_bf16(ac[m], xc, z, 0, 0, 0);
#pragma unroll
      for (int m = 0; m < 4; ++m) {
        f32x4 pm = d[m] * v[m];
        float p = (pm[0] + pm[1]) + (pm[2] + pm[3]);
        p += __shfl_xor(p, 16);
        p += __shfl_xor(p, 32);
        e[m] = __expf(p);
      }
      if (q == 0) part[s0][w][bl] = (e[0] + e[1]) + (e[2] + e[3]);
#pragma unroll
      for (int m = 0; m < 4; ++m) dk0[m] = d[m] * e[m];   // pre-scale by e
    }
    {                                        // ---- half 1 (ii = 2*pr2+1) ----
      const int ii = 2 * pr2 + 1;
      short8 ac[4];
      short8 xc = xn;
#pragma unroll
      for (int m = 0; m < 4; ++m) ac[m] = an[m];
      if (ii + 1 < IPC) {                    // prefetch rides across barrier
        xn = ld_x(xs, ii + 1, l);
#pragma unroll
        for (int m = 0; m < 4; ++m) an[m] = wp[m * 32];
        wp += 1024;
      }
      const f32x4 z = {0.f, 0.f, 0.f, 0.f};
      f32x4 d[4];
      float e[4];
#pragma unroll
      for (int m = 0; m < 4; ++m)
        d[m] = __builtin_amdgcn_mfma_f32_16x16x32_bf16(ac[m], xc, z, 0, 0, 0);
#pragma unroll
      for (int m = 0; m < 4; ++m) {
        f32x4 pm = d[m] * v[m];
        float p = (pm[0] + pm[1]) + (pm[2] + pm[3]);
        p += __shfl_xor(p, 16);
        p += __shfl_xor(p, 32);
        e[m] = __expf(p);
      }
      if (q == 0) part[s0 + 1][w][bl] = (e[0] + e[1]) + (e[2] + e[3]);
#pragma unroll
      for (int m = 0; m < 4; ++m) dk1[m] = d[m] * e[m];
    }
    __syncthreads();                         // one barrier per TWO routing-i
    float den0 = 0.f, den1 = 0.f;
#pragma unroll
    for (int ww = 0; ww < 8; ++ww) {
      den0 += part[s0][ww][bl];
      den1 += part[s0 + 1][ww][bl];
    }
    const float r0 = __builtin_amdgcn_rcpf(den0);
    const float r1 = __builtin_amdgcn_rcpf(den1);
#pragma unroll
    for (int m = 0; m < 4; ++m) sacc[m] += dk0[m] * r0 + dk1[m] * r1;
  }

#pragma unroll
  for (int m = 0; m < 4; ++m) *(f32x4*)(pp + m * 16) = sacc[m];
}

// ---- reduce over iblk + squash (512-thread form, red[16][32] LDS).
// MODE 0: V1p + Vt. 1: Vt = V1p+sq. 2: Out. ----
template <int MODE>
__device__ __forceinline__ void reduce_phase(const float* __restrict__ P,
                                             float* __restrict__ Vt,
                                             float* __restrict__ V1p,
                                             float* __restrict__ Out,
                                             int bid, int t, f32x4 (*red)[32]) {
  const int qd = t & 31, kq = t >> 5;              // kq 0..15
  const int j4 = bid * 32 + qd;                    // quad index, 0..16383
  const f32x4* p = (const f32x4*)P + j4 + (size_t)kq * 4 * (SV_ELEMS / 4);
  f32x4 s = {0.f, 0.f, 0.f, 0.f};
#pragma unroll
  for (int k = 0; k < 4; ++k) s += p[(size_t)k * (SV_ELEMS / 4)];
  red[kq][qd] = s;
  __syncthreads();
  if (t < 32) {
    f32x4 a = red[0][t];
#pragma unroll
    for (int k2 = 1; k2 < 16; ++k2) a += red[k2][t];
    // norm over 16 h: 4 in-thread + quads j4^1, j4^2 (h-quarters)
    float ns = a[0] * a[0] + a[1] * a[1] + a[2] * a[2] + a[3] * a[3];
    ns += __shfl_xor(ns, 1);
    ns += __shfl_xor(ns, 2);
    const float sc = ns / ((1.f + ns) * sqrtf(ns));
    f32x4 vv = a * sc;
    if constexpr (MODE == 2) {
      ((f32x4*)Out)[j4] = vv;
    } else {
      if constexpr (MODE == 0) ((f32x4*)V1p)[j4] = vv;
      if constexpr (MODE == 1) vv += ((const f32x4*)V1p)[j4];
#pragma unroll
      for (int c = 0; c < 4; ++c) {
        const int j = j4 * 4 + c;
        const int b = j >> 9, oh = j & 511, o = oh >> 4, h = oh & 15;
        const int bg = b >> 4, bl = b & 15, w = o >> 2, m = o & 3, qq = h >> 2;
        Vt[(((size_t)(bg * 8 + w) * 64 + qq * 16 + bl) * 16) + m * 4 + (h & 3)] =
            vv[c];
      }
    }
  }
  __syncthreads();                                 // red free for next phase
}

// =================== fused kernel, hand-rolled barriers ===================
__global__ __launch_bounds__(512, 4)
void caps_one(const float* __restrict__ W, const float* __restrict__ X,
              unsigned short* __restrict__ Wb, float* __restrict__ P,
              float* __restrict__ Vt, float* __restrict__ V1p,
              float* __restrict__ Out, unsigned* __restrict__ ctr) {
  // LDS union: conv st (33024B) overlaps xs(18432) + part(2048) + red(8192)
  __shared__ __align__(16) char smem[16 * 516 * 4];
  float* st = (float*)smem;
  unsigned (*xs)[64][4] = (unsigned (*)[64][4])smem;
  float (*part)[8][16] = (float (*)[8][16])(smem + 18432);
  f32x4 (*red)[32] = (f32x4(*)[32])(smem + 18432 + 2048);

  const int t = threadIdx.x, w = t >> 6, l = t & 63;
  const int q = l >> 4, bl = l & 15;
  const int bid = blockIdx.x, iblk = bid & 63, sub = bid >> 6, bg = sub;
  const int i0 = iblk * IPC;

  // phase 0: W -> Wb for this block's iblk, ii%8==sub (XCD-aligned: this
  // block and the pass-phase consumers of Wb[iblk] share bid%8==iblk%8).
  for (int ii = sub; ii < IPC; ii += 8) conv_i(W, Wb, st, i0 + ii, t);

  // stage X fragments ONCE (st dead; conv_i's trailing barrier fences reuse)
  build_xs(X, bg, i0, t, xs);
  // grid_bar's leading __syncthreads fences xs-ready

  const short8* wpb = (const short8*)Wb + ((size_t)i0 * 32 + w * 4) * 32 + (l & 31);
  float* pp = P + ((size_t)iblk * 128 + bg * 16 + bl) * 512 + w * 64 + q * 4;

  grid_bar(ctr, GRID * 1, t);                       // Wb complete everywhere
  pass1_phase(wpb, xs, pp, l);                      // routing iter 1
  grid_bar(ctr, GRID * 2, t);
  reduce_phase<0>(P, Vt, V1p, nullptr, bid, t, red);
  grid_bar(ctr, GRID * 3, t);
  pass23_phase(wpb, xs, part, Vt, pp, bg, w, l, q, bl);  // routing iter 2
  grid_bar(ctr, GRID * 4, t);
  reduce_phase<1>(P, Vt, V1p, nullptr, bid, t, red);
  grid_bar(ctr, GRID * 5, t);
  pass23_phase(wpb, xs, part, Vt, pp, bg, w, l, q, bl);  // routing iter 3
  grid_bar(ctr, GRID * 6, t);
  reduce_phase<2>(P, nullptr, nullptr, Out, bid, t, red);
}

// =================== fallback: round-7 kernels (verified) ===================
__global__ __launch_bounds__(256) void conv_w(const float* __restrict__ W,
                                              unsigned short* __restrict__ Wb) {
  __shared__ float st[16 * 516];
  const int t = threadIdx.x;
  const size_t ibase = (size_t)blockIdx.x * 8192;
  const float4* src = (const float4*)(W + ibase);
#pragma unroll
  for (int r = 0; r < 8; ++r) {
    const int f = r * 256 + t;
    const int k = f >> 7, c4 = f & 127;
    *(float4*)&st[k * 516 + c4 * 4] = src[f];
  }
  __syncthreads();
  unsigned short* dst = Wb + ibase;
#pragma unroll
  for (int r = 0; r < 4; ++r) {
    const int u = r * 256 + t;
    const int o = u >> 5, l = u & 31;
    const int col = o * 16 + (l & 15), k0 = (l >> 4) * 8;
    unsigned b[8];
#pragma unroll
    for (int j = 0; j < 8; ++j) b[j] = f2bf(st[(k0 + j) * 516 + col]);
    uint4 outv;
    outv.x = b[0] | (b[1] << 16);
    outv.y = b[2] | (b[3] << 16);
    outv.z = b[4] | (b[5] << 16);
    outv.w = b[6] | (b[7] << 16);
    *(uint4*)(dst + (size_t)u * 8) = outv;
  }
}

__global__ __launch_bounds__(512, 4)
void caps_pass1(const unsigned short* __restrict__ Wb,
                const float* __restrict__ X, float* __restrict__ P) {
  __shared__ __align__(16) unsigned xs[IPC][64][4];
  const int t = threadIdx.x, w = t >> 6, l = t & 63;
  const int q = l >> 4, bl = l & 15;
  const int gx = blockIdx.x, iblk = gx & 63, bg = gx >> 6;
  const int i0 = iblk * IPC;
  build_xs(X, bg, i0, t, xs);
  __syncthreads();
  const short8* wpb = (const short8*)Wb + ((size_t)i0 * 32 + w * 4) * 32 + (l & 31);
  float* pp = P + ((size_t)iblk * 128 + bg * 16 + bl) * 512 + w * 64 + q * 4;
  pass1_phase(wpb, xs, pp, l);
}

__global__ __launch_bounds__(512, 4)
void caps_pass23(const unsigned short* __restrict__ Wb,
                 const float* __restrict__ X,
                 const float* __restrict__ Vt, float* __restrict__ P) {
  __shared__ __align__(16) unsigned xs[IPC][64][4];
  __shared__ float part[4][8][16];
  const int t = threadIdx.x, w = t >> 6, l = t & 63;
  const int q = l >> 4, bl = l & 15;
  const int gx = blockIdx.x, iblk = gx & 63, bg = gx >> 6;
  const int i0 = iblk * IPC;
  build_xs(X, bg, i0, t, xs);
  __syncthreads();
  const short8* wpb = (const short8*)Wb + ((size_t)i0 * 32 + w * 4) * 32 + (l & 31);
  float* pp = P + ((size_t)iblk * 128 + bg * 16 + bl) * 512 + w * 64 + q * 4;
  pass23_phase(wpb, xs, part, Vt, pp, bg, w, l, q, bl);
}

template <int MODE>
__global__ __launch_bounds__(256)
void reduce_squash(const float* __restrict__ P, float* __restrict__ Vt,
                   float* __restrict__ V1p, float* __restrict__ Out) {
  __shared__ f32x4 red[8][32];
  const int t = threadIdx.x, qd = t & 31, kq = t >> 5;
  const int j4 = blockIdx.x * 32 + qd;
  const f32x4* p = (const f32x4*)P + j4 + (size_t)kq * 8 * (SV_ELEMS / 4);
  f32x4 s = {0.f, 0.f, 0.f, 0.f};
#pragma unroll
  for (int k = 0; k < 8; ++k) s += p[(size_t)k * (SV_ELEMS / 4)];
  red[kq][qd] = s;
  __syncthreads();
  if (t < 32) {
    f32x4 a = red[0][t];
#pragma unroll
    for (int k2 = 1; k2 < 8; ++k2) a += red[k2][t];
    float ns = a[0] * a[0] + a[1] * a[1] + a[2] * a[2] + a[3] * a[3];
    ns += __shfl_xor(ns, 1);
    ns += __shfl_xor(ns, 2);
    const float sc = ns / ((1.f + ns) * sqrtf(ns));
    f32x4 vv = a * sc;
    if constexpr (MODE == 2) {
      ((f32x4*)Out)[j4] = vv;
    } else {
      if constexpr (MODE == 0) ((f32x4*)V1p)[j4] = vv;
      if constexpr (MODE == 1) vv += ((const f32x4*)V1p)[j4];
#pragma unroll
      for (int c = 0; c < 4; ++c) {
        const int j = j4 * 4 + c;
        const int b = j >> 9, oh = j & 511, o = oh >> 4, h = oh & 15;
        const int bg = b >> 4, bl = b & 15, w = o >> 2, m = o & 3, qq = h >> 2;
        Vt[(((size_t)(bg * 8 + w) * 64 + qq * 16 + bl) * 16) + m * 4 + (h & 3)] =
            vv[c];
      }
    }
  }
}

extern "C" void kernel_launch(void* const* d_in, const int* in_sizes, int n_in,
                              void* d_out, int out_size, void* d_ws, size_t ws_size,
                              hipStream_t stream) {
  const float* X  = (const float*)d_in[0];
  const float* Wg = (const float*)d_in[1];
  // d_in[2] = routing_iterations (3, hard-coded)

  float* P   = (float*)d_ws;                         // 64*65536 f = 16.8 MB
  float* Vt  = P + (size_t)NBLK_I * SV_ELEMS;        // 65536 f (frag order)
  float* V1p = Vt + SV_ELEMS;                        // 65536 f (plain)
  unsigned short* Wb = (unsigned short*)(V1p + SV_ELEMS);   // 18.9 MB
  unsigned* ctr = (unsigned*)(Wb + (size_t)IN_CAPS * 8192); // barrier counter
  float* out = (float*)d_out;                        // total ws ~34.5 MB

  hipMemsetAsync(ctr, 0, 64, stream);                // ws is re-poisoned

  void* args[] = {(void*)&Wg, (void*)&X, (void*)&Wb, (void*)&P,
                  (void*)&Vt, (void*)&V1p, (void*)&out, (void*)&ctr};
  hipError_t err = hipLaunchCooperativeKernel((void*)caps_one, dim3(GRID),
                                              dim3(512), args, 0, stream);
  if (err != hipSuccess) {
    (void)hipGetLastError();                         // clear, take 7-kernel path
    conv_w<<<IN_CAPS, 256, 0, stream>>>(Wg, Wb);
    caps_pass1<<<512, 512, 0, stream>>>(Wb, X, P);
    reduce_squash<0><<<512, 256, 0, stream>>>(P, Vt, V1p, nullptr);
    caps_pass23<<<512, 512, 0, stream>>>(Wb, X, Vt, P);
    reduce_squash<1><<<512, 256, 0, stream>>>(P, Vt, V1p, nullptr);
    caps_pass23<<<512, 512, 0, stream>>>(Wb, X, Vt, P);
    reduce_squash<2><<<512, 256, 0, stream>>>(P, nullptr, nullptr, out);
  }
}

// Round 4
// 172.305 us; speedup vs baseline: 2.7345x; 2.7345x over previous
//
#include <hip/hip_runtime.h>
#include <hip/hip_bf16.h>

// CapsuleLayerWithRouting: batch=128, in_caps=1152, in_hid=16, out_caps=32,
// out_hid=16, 3 routing iterations (fixed). fp32 in/out.
//
// Round-9: multi-kernel (fusion proven structurally dead: r6 cg-sync and r8
// hand-rolled barrier BOTH cost ~55us/barrier -> per-block agent-scope
// acquire/release forces redundant per-XCD L2 writeback/invalidate; kernel
// boundaries are the cheapest coherence flush on gfx950).
// This round: NBLK_I 64 -> 32 (IPC 36). Halves the P-partials round trips
// (16.8 -> 8.4 MB per write/read, x3 iterations, ~-4us) and halves each
// reduce kernel's read volume. Pass grids 512 -> 256 blocks (1 block/CU);
// passes are L2/L3-BW-bound streams so per-CU byte flow is unchanged.
// Everything else identical to the verified round-7 kernel (161.4us):
//  - pass23: 2 routing-i per __syncthreads via 4-slot part[] ring
//  - reduce: float4 loads, 8-way k-split, LDS combine
//  - conv_w: LDS-staged transpose, coalesced both sides (unchanged)
// Fragment layouts (HW-verified m89/m91):
//   A[m=lane&15][k=(lane>>4)*8+j]  B[k=(lane>>4)*8+j][n=lane&15]
//   D[row=(lane>>4)*4+reg][col=lane&15]

#define IN_CAPS 1152
#define OUT_CAPS 32
#define BATCH 128
#define IPC 36
#define NBLK_I (IN_CAPS / IPC)               // 32
#define SV_ELEMS (BATCH * OUT_CAPS * 16)     // 65536

typedef __attribute__((ext_vector_type(8))) short short8;
typedef __attribute__((ext_vector_type(4))) float f32x4;

__device__ inline unsigned f2bf(float x) {          // RNE fp32 -> bf16
  unsigned u = __builtin_bit_cast(unsigned, x);
  return (u + 0x7FFFu + ((u >> 16) & 1u)) >> 16;
}

// ---- W [1152][16][512] fp32 -> Wb [i][o][lane(32)][8] bf16 (A-frag). ----
// One i per block; LDS-staged so global reads and writes are both coalesced.
__global__ __launch_bounds__(256) void conv_w(const float* __restrict__ W,
                                              unsigned short* __restrict__ Wb) {
  __shared__ float st[16 * 516];              // stride 516: 2-way banks only
  const int t = threadIdx.x;
  const size_t ibase = (size_t)blockIdx.x * 8192;
  const float4* src = (const float4*)(W + ibase);
#pragma unroll
  for (int r = 0; r < 8; ++r) {
    const int f = r * 256 + t;                // 0..2047 float4s
    const int k = f >> 7, c4 = f & 127;
    *(float4*)&st[k * 516 + c4 * 4] = src[f];
  }
  __syncthreads();
  unsigned short* dst = Wb + ibase;
#pragma unroll
  for (int r = 0; r < 4; ++r) {
    const int u = r * 256 + t;                // 0..1023 = o*32 + l
    const int o = u >> 5, l = u & 31;
    const int col = o * 16 + (l & 15), k0 = (l >> 4) * 8;
    unsigned b[8];
#pragma unroll
    for (int j = 0; j < 8; ++j) b[j] = f2bf(st[(k0 + j) * 516 + col]);
    uint4 outv;
    outv.x = b[0] | (b[1] << 16);
    outv.y = b[2] | (b[3] << 16);
    outv.z = b[4] | (b[5] << 16);
    outv.w = b[6] | (b[7] << 16);
    *(uint4*)(dst + (size_t)u * 8) = outv;    // consecutive u -> coalesced
  }
}

// ---- build x B-fragment slice in LDS: xs[i][lane][4 uints] (16B/lane),
// zeros in lanes 32-63 (the k=16..31 zero pad) ----
__device__ __forceinline__ void build_xs(const float* __restrict__ X, int bg,
                                         int i0, int t, unsigned (*xs)[64][4]) {
#pragma unroll
  for (int rep = 0; rep < IPC * 256 / 512; ++rep) {
    const int base = rep * 512 + t;
    const int ii = base >> 8;
    const int e = base & 255;
    const int l2 = e >> 2, ju = e & 3;
    unsigned val = 0;
    if (l2 < 32) {
      const float2 f = *(const float2*)(X +
          ((size_t)(bg * 16 + (l2 & 15)) * IN_CAPS + (i0 + ii)) * 16 +
          (l2 >> 4) * 8 + 2 * ju);
      val = f2bf(f.x) | (f2bf(f.y) << 16);
    }
    xs[ii][l2][ju] = val;
  }
}

__device__ __forceinline__ short8 ld_x(const unsigned (*xs)[64][4], int ii, int l) {
  return __builtin_bit_cast(short8, *(const uint4*)(&xs[ii][l][0]));
}

// ---- pass 1: C = 1/32 uniform -> S1 partials ----
__global__ __launch_bounds__(512, 4)
void caps_pass1(const unsigned short* __restrict__ Wb,
                const float* __restrict__ X, float* __restrict__ P) {
  __shared__ __align__(16) unsigned xs[IPC][64][4];
  const int t = threadIdx.x, w = t >> 6, l = t & 63;
  const int q = l >> 4, bl = l & 15;
  const int gx = blockIdx.x, iblk = gx & (NBLK_I - 1), bg = gx >> 5;
  const int i0 = iblk * IPC;

  build_xs(X, bg, i0, t, xs);
  __syncthreads();

  const short8* wp = (const short8*)Wb + ((size_t)i0 * 32 + w * 4) * 32 + (l & 31);
  f32x4 sacc[4];
#pragma unroll
  for (int m = 0; m < 4; ++m) sacc[m] = (f32x4){0.f, 0.f, 0.f, 0.f};

  for (int ii = 0; ii < IPC; ++ii) {
    short8 x = ld_x(xs, ii, l);
    short8 a0 = wp[0], a1 = wp[32], a2 = wp[64], a3 = wp[96];
    wp += 1024;
    sacc[0] = __builtin_amdgcn_mfma_f32_16x16x32_bf16(a0, x, sacc[0], 0, 0, 0);
    sacc[1] = __builtin_amdgcn_mfma_f32_16x16x32_bf16(a1, x, sacc[1], 0, 0, 0);
    sacc[2] = __builtin_amdgcn_mfma_f32_16x16x32_bf16(a2, x, sacc[2], 0, 0, 0);
    sacc[3] = __builtin_amdgcn_mfma_f32_16x16x32_bf16(a3, x, sacc[3], 0, 0, 0);
  }
  float* pp = P + ((size_t)iblk * 128 + bg * 16 + bl) * 512 + w * 64 + q * 4;
#pragma unroll
  for (int m = 0; m < 4; ++m) *(f32x4*)(pp + m * 16) = sacc[m] * (1.f / 32.f);
}

// ---- passes 2/3: dot = u.V; C = softmax(dot); S += C*u.
// Two routing-i per barrier; part[] is a 4-slot ring so a slot is rewritten
// two pairs later, always with an intervening barrier (WAR-safe). ----
__global__ __launch_bounds__(512, 4)
void caps_pass23(const unsigned short* __restrict__ Wb,
                 const float* __restrict__ X,
                 const float* __restrict__ Vt,   // fragment order
                 float* __restrict__ P) {
  __shared__ __align__(16) unsigned xs[IPC][64][4];
  __shared__ float part[4][8][16];
  const int t = threadIdx.x, w = t >> 6, l = t & 63;
  const int q = l >> 4, bl = l & 15;
  const int gx = blockIdx.x, iblk = gx & (NBLK_I - 1), bg = gx >> 5;
  const int i0 = iblk * IPC;

  f32x4 v[4], sacc[4];
#pragma unroll
  for (int m = 0; m < 4; ++m) {
    v[m] = ((const f32x4*)Vt)[((size_t)(bg * 8 + w) * 64 + l) * 4 + m];
    sacc[m] = (f32x4){0.f, 0.f, 0.f, 0.f};
  }

  build_xs(X, bg, i0, t, xs);
  __syncthreads();

  const short8* wp = (const short8*)Wb + ((size_t)i0 * 32 + w * 4) * 32 + (l & 31);
  short8 an[4];
  short8 xn = ld_x(xs, 0, l);
#pragma unroll
  for (int m = 0; m < 4; ++m) an[m] = wp[m * 32];
  wp += 1024;

  for (int pr2 = 0; pr2 < IPC / 2; ++pr2) {
    f32x4 dk0[4], dk1[4];
    const int s0 = (pr2 & 1) * 2;            // part slot pair for this pr2
    // ---- half 0 (ii = 2*pr2) ----
    {
      short8 ac[4];
      short8 xc = xn;
#pragma unroll
      for (int m = 0; m < 4; ++m) ac[m] = an[m];
      xn = ld_x(xs, 2 * pr2 + 1, l);         // always valid (<= IPC-1)
#pragma unroll
      for (int m = 0; m < 4; ++m) an[m] = wp[m * 32];
      wp += 1024;
      const f32x4 z = {0.f, 0.f, 0.f, 0.f};
      f32x4 d[4];
      float e[4];
#pragma unroll
      for (int m = 0; m < 4; ++m)
        d[m] = __builtin_amdgcn_mfma_f32_16x16x32_bf16(ac[m], xc, z, 0, 0, 0);
#pragma unroll
      for (int m = 0; m < 4; ++m) {
        f32x4 pm = d[m] * v[m];
        float p = (pm[0] + pm[1]) + (pm[2] + pm[3]);
        p += __shfl_xor(p, 16);
        p += __shfl_xor(p, 32);
        e[m] = __expf(p);
      }
      if (q == 0) part[s0][w][bl] = (e[0] + e[1]) + (e[2] + e[3]);
#pragma unroll
      for (int m = 0; m < 4; ++m) dk0[m] = d[m] * e[m];   // pre-scale by e
    }
    // ---- half 1 (ii = 2*pr2+1); its MFMAs issue BEFORE the barrier ----
    {
      const int ii = 2 * pr2 + 1;
      short8 ac[4];
      short8 xc = xn;
#pragma unroll
      for (int m = 0; m < 4; ++m) ac[m] = an[m];
      if (ii + 1 < IPC) {                    // prefetch rides across barrier
        xn = ld_x(xs, ii + 1, l);
#pragma unroll
        for (int m = 0; m < 4; ++m) an[m] = wp[m * 32];
        wp += 1024;
      }
      const f32x4 z = {0.f, 0.f, 0.f, 0.f};
      f32x4 d[4];
      float e[4];
#pragma unroll
      for (int m = 0; m < 4; ++m)
        d[m] = __builtin_amdgcn_mfma_f32_16x16x32_bf16(ac[m], xc, z, 0, 0, 0);
#pragma unroll
      for (int m = 0; m < 4; ++m) {
        f32x4 pm = d[m] * v[m];
        float p = (pm[0] + pm[1]) + (pm[2] + pm[3]);
        p += __shfl_xor(p, 16);
        p += __shfl_xor(p, 32);
        e[m] = __expf(p);
      }
      if (q == 0) part[s0 + 1][w][bl] = (e[0] + e[1]) + (e[2] + e[3]);
#pragma unroll
      for (int m = 0; m < 4; ++m) dk1[m] = d[m] * e[m];
    }
    __syncthreads();                         // one barrier per TWO routing-i
    float den0 = 0.f, den1 = 0.f;
#pragma unroll
    for (int ww = 0; ww < 8; ++ww) {
      den0 += part[s0][ww][bl];
      den1 += part[s0 + 1][ww][bl];
    }
    const float r0 = __builtin_amdgcn_rcpf(den0);
    const float r1 = __builtin_amdgcn_rcpf(den1);
#pragma unroll
    for (int m = 0; m < 4; ++m) sacc[m] += dk0[m] * r0 + dk1[m] * r1;
    // slot pair s0 is rewritten two pairs later; the next pair's barrier
    // sits between this read and that write (same fencing as old parity).
  }

  float* pp = P + ((size_t)iblk * 128 + bg * 16 + bl) * 512 + w * 64 + q * 4;
#pragma unroll
  for (int m = 0; m < 4; ++m) *(f32x4*)(pp + m * 16) = sacc[m];
}

// ---- reduce over iblk + squash. MODE 0: V1p + Vt. 1: Vt = V1p+sq. 2: Out.
// float4 loads, k-loop split 8-way across the block, 512-block spread. ----
template <int MODE>
__global__ __launch_bounds__(256)
void reduce_squash(const float* __restrict__ P, float* __restrict__ Vt,
                   float* __restrict__ V1p, float* __restrict__ Out) {
  __shared__ f32x4 red[8][32];
  const int t = threadIdx.x, qd = t & 31, kq = t >> 5;
  const int j4 = blockIdx.x * 32 + qd;             // quad index, 0..16383
  const f32x4* p = (const f32x4*)P + j4 + (size_t)kq * 4 * (SV_ELEMS / 4);
  f32x4 s = {0.f, 0.f, 0.f, 0.f};
#pragma unroll
  for (int k = 0; k < 4; ++k) s += p[(size_t)k * (SV_ELEMS / 4)];
  red[kq][qd] = s;
  __syncthreads();
  if (t < 32) {
    f32x4 a = red[0][t];
#pragma unroll
    for (int k2 = 1; k2 < 8; ++k2) a += red[k2][t];
    // norm over 16 h: 4 in-thread + quads j4^1, j4^2 (h-quarters)
    float ns = a[0] * a[0] + a[1] * a[1] + a[2] * a[2] + a[3] * a[3];
    ns += __shfl_xor(ns, 1);
    ns += __shfl_xor(ns, 2);
    const float sc = ns / ((1.f + ns) * sqrtf(ns));
    f32x4 vv = a * sc;
    if constexpr (MODE == 2) {
      ((f32x4*)Out)[j4] = vv;
    } else {
      if constexpr (MODE == 0) ((f32x4*)V1p)[j4] = vv;
      if constexpr (MODE == 1) vv += ((const f32x4*)V1p)[j4];
#pragma unroll
      for (int c = 0; c < 4; ++c) {
        const int j = j4 * 4 + c;
        const int b = j >> 9, oh = j & 511, o = oh >> 4, h = oh & 15;
        const int bg = b >> 4, bl = b & 15, w = o >> 2, m = o & 3, qq = h >> 2;
        Vt[(((size_t)(bg * 8 + w) * 64 + qq * 16 + bl) * 16) + m * 4 + (h & 3)] =
            vv[c];
      }
    }
  }
}

extern "C" void kernel_launch(void* const* d_in, const int* in_sizes, int n_in,
                              void* d_out, int out_size, void* d_ws, size_t ws_size,
                              hipStream_t stream) {
  const float* X  = (const float*)d_in[0];
  const float* Wg = (const float*)d_in[1];
  // d_in[2] = routing_iterations (3, hard-coded)

  float* P   = (float*)d_ws;                         // 32*65536 f = 8.4 MB
  float* Vt  = P + (size_t)NBLK_I * SV_ELEMS;        // 65536 f (frag order)
  float* V1p = Vt + SV_ELEMS;                        // 65536 f (plain)
  unsigned short* Wb = (unsigned short*)(V1p + SV_ELEMS);   // 18.9 MB
  float* out = (float*)d_out;                        // total ws ~27.9 MB

  conv_w<<<IN_CAPS, 256, 0, stream>>>(Wg, Wb);

  caps_pass1<<<NBLK_I * 8, 512, 0, stream>>>(Wb, X, P);
  reduce_squash<0><<<512, 256, 0, stream>>>(P, Vt, V1p, nullptr);

  caps_pass23<<<NBLK_I * 8, 512, 0, stream>>>(Wb, X, Vt, P);
  reduce_squash<1><<<512, 256, 0, stream>>>(P, Vt, V1p, nullptr);

  caps_pass23<<<NBLK_I * 8, 512, 0, stream>>>(Wb, X, Vt, P);
  reduce_squash<2><<<512, 256, 0, stream>>>(P, nullptr, nullptr, out);
}

// Round 5
// 150.456 us; speedup vs baseline: 3.1316x; 1.1452x over previous
//
#include <hip/hip_runtime.h>
#include <hip/hip_bf16.h>

// CapsuleLayerWithRouting: batch=128, in_caps=1152, in_hid=16, out_caps=32,
// out_hid=16, 3 routing iterations (fixed). fp32 in/out.
//
// Round-10: revert r9's NBLK regression (occupancy > P-traffic: 1 blk/CU
// cost +11us) back to NBLK_I=64 / 512-block passes, then cut pass VALU:
//  - PACKED-K fragments: 16x16x32 MFMA previously wasted k=16..31 on zeros.
//    conv_w now packs W[i0] in k<16 and W[i1] in k>=16 (64 distinct lanes).
//    pass1 contracts an i-PAIR per MFMA (18->9 MFMAs/loads per o; the pair
//    sum is exactly pass1's uniform-C sum). pass23 keeps i's separate by
//    masking x halves (x0 = x&zm, x1 = x^x0) from ONE LDS pair-load;
//    A-loads halve. xs LDS halves to 9KB.
//  - sacc += d*(e*rden) post-barrier (scalar fold; 64->40 ops/pair)
//  - part[4][16][8]: den = 2x ds_read_b128 + hsum (was 8 scalar loads)
//  - exp2 path: Vt pre-scaled by log2e in reduce; native exp2 in pass23;
//    ds_swizzle imm for the lane^16 dot-reduce hop.
// Fragment layouts (HW-verified m89/m91):
//   A[m=lane&15][k=(lane>>4)*8+j]  B[k=(lane>>4)*8+j][n=lane&15]
//   D[row=(lane>>4)*4+reg][col=lane&15]

#define IN_CAPS 1152
#define OUT_CAPS 32
#define BATCH 128
#define IPC 18
#define PAIRS (IPC / 2)                      // 9
#define NBLK_I (IN_CAPS / IPC)               // 64
#define SV_ELEMS (BATCH * OUT_CAPS * 16)     // 65536
#define LOG2E 1.4426950408889634f

typedef __attribute__((ext_vector_type(8))) short short8;
typedef __attribute__((ext_vector_type(4))) float f32x4;

#if __has_builtin(__builtin_amdgcn_exp2f)
#define EXP2(x) __builtin_amdgcn_exp2f(x)
#else
#define EXP2(x) exp2f(x)
#endif

__device__ inline unsigned f2bf(float x) {          // RNE fp32 -> bf16
  unsigned u = __builtin_bit_cast(unsigned, x);
  return (u + 0x7FFFu + ((u >> 16) & 1u)) >> 16;
}

__device__ __forceinline__ float swz16_add(float p) {  // p += lane^16 partner
  const int pi = __builtin_bit_cast(int, p);
  return p + __builtin_bit_cast(float,
             __builtin_amdgcn_ds_swizzle(pi, 0x401F));  // xor-16, and 0x1F
}

// ---- W [1152][16][512] fp32 -> packed A-frags:
// Wb[pair][o][lane64][8] bf16, k<16 = W[2p], k>=16 = W[2p+1]. ----
__global__ __launch_bounds__(256) void conv_w(const float* __restrict__ W,
                                              unsigned short* __restrict__ Wb) {
  __shared__ float st[32 * 516];              // 66KB; rows 0..15 = i0, 16..31 = i1
  const int t = threadIdx.x;
  const float4* src = (const float4*)(W + (size_t)blockIdx.x * 16384);
#pragma unroll
  for (int r = 0; r < 16; ++r) {
    const int f = r * 256 + t;                // 0..4095 float4s
    const int k = f >> 7, c4 = f & 127;       // k = i_off*16 + hi
    *(float4*)&st[k * 516 + c4 * 4] = src[f];
  }
  __syncthreads();
  uint4* dst = (uint4*)(Wb + (size_t)blockIdx.x * 16384);
#pragma unroll
  for (int r = 0; r < 8; ++r) {
    const int u = r * 256 + t;                // 0..2047 = o*64 + l
    const int o = u >> 6, l = u & 63;
    const int col = o * 16 + (l & 15), k0 = (l >> 4) * 8;   // k0 in 0..31
    unsigned b[8];
#pragma unroll
    for (int j = 0; j < 8; ++j) b[j] = f2bf(st[(k0 + j) * 516 + col]);
    uint4 outv;
    outv.x = b[0] | (b[1] << 16);
    outv.y = b[2] | (b[3] << 16);
    outv.z = b[4] | (b[5] << 16);
    outv.w = b[6] | (b[7] << 16);
    dst[u] = outv;                            // consecutive u -> coalesced
  }
}

// ---- xs[i][lane32][4 uints]: B-frag rows k=0..15 only (16B per lane). ----
__device__ __forceinline__ void build_xs(const float* __restrict__ X, int bg,
                                         int i0, int t, unsigned (*xs)[32][4]) {
#pragma unroll
  for (int rep = 0; rep < 5; ++rep) {
    const int idx = rep * 512 + t;
    if (idx < IPC * 128) {
      const int ii = idx >> 7;
      const int e = idx & 127;
      const int l2 = e >> 2, ju = e & 3;
      const float2 f = *(const float2*)(X +
          ((size_t)(bg * 16 + (l2 & 15)) * IN_CAPS + (i0 + ii)) * 16 +
          (l2 >> 4) * 8 + 2 * ju);
      xs[ii][l2][ju] = f2bf(f.x) | (f2bf(f.y) << 16);
    }
  }
}

// pair-load: lanes 0-31 read row 2pr (k=0..15 <- i0), lanes 32-63 read row
// 2pr+1 (k=16..31 <- i1). One LDS read, no select.
__device__ __forceinline__ uint4 ld_x_pair(const unsigned (*xs)[32][4],
                                           int pr, int l) {
  return *(const uint4*)(&xs[2 * pr + (l >> 5)][l & 31][0]);
}

__device__ __forceinline__ short8 u4s8(uint4 v) {
  return __builtin_bit_cast(short8, v);
}

// ---- pass 1: C = 1/32 uniform -> S1 partials. One MFMA per i-PAIR. ----
__global__ __launch_bounds__(512, 4)
void caps_pass1(const unsigned short* __restrict__ Wb,
                const float* __restrict__ X, float* __restrict__ P) {
  __shared__ __align__(16) unsigned xs[IPC][32][4];
  const int t = threadIdx.x, w = t >> 6, l = t & 63;
  const int q = l >> 4, bl = l & 15;
  const int gx = blockIdx.x, iblk = gx & 63, bg = gx >> 6;
  const int i0 = iblk * IPC;

  build_xs(X, bg, i0, t, xs);
  __syncthreads();

  const short8* wp = (const short8*)Wb +
      ((size_t)iblk * PAIRS) * 2048 + w * 256 + l;
  f32x4 sacc[4];
#pragma unroll
  for (int m = 0; m < 4; ++m) sacc[m] = (f32x4){0.f, 0.f, 0.f, 0.f};

  for (int pr = 0; pr < PAIRS; ++pr) {
    short8 x = u4s8(ld_x_pair(xs, pr, l));
    short8 a0 = wp[0], a1 = wp[64], a2 = wp[128], a3 = wp[192];
    wp += 2048;
    sacc[0] = __builtin_amdgcn_mfma_f32_16x16x32_bf16(a0, x, sacc[0], 0, 0, 0);
    sacc[1] = __builtin_amdgcn_mfma_f32_16x16x32_bf16(a1, x, sacc[1], 0, 0, 0);
    sacc[2] = __builtin_amdgcn_mfma_f32_16x16x32_bf16(a2, x, sacc[2], 0, 0, 0);
    sacc[3] = __builtin_amdgcn_mfma_f32_16x16x32_bf16(a3, x, sacc[3], 0, 0, 0);
  }
  float* pp = P + ((size_t)iblk * 128 + bg * 16 + bl) * 512 + w * 64 + q * 4;
#pragma unroll
  for (int m = 0; m < 4; ++m) *(f32x4*)(pp + m * 16) = sacc[m] * (1.f / 32.f);
}

// ---- passes 2/3: dot = u.V (Vt pre-scaled by log2e); C = softmax; S += C*u.
// One i-pair per barrier; part[] is a 4-slot ring (WAR fenced 2 deep). ----
__global__ __launch_bounds__(512, 4)
void caps_pass23(const unsigned short* __restrict__ Wb,
                 const float* __restrict__ X,
                 const float* __restrict__ Vt,   // fragment order, * log2e
                 float* __restrict__ P) {
  __shared__ __align__(16) unsigned xs[IPC][32][4];
  __shared__ float part[4][16][8];           // [slot][bl][w]
  const int t = threadIdx.x, w = t >> 6, l = t & 63;
  const int q = l >> 4, bl = l & 15;
  const int gx = blockIdx.x, iblk = gx & 63, bg = gx >> 6;
  const int i0 = iblk * IPC;

  f32x4 v[4], sacc[4];
#pragma unroll
  for (int m = 0; m < 4; ++m) {
    v[m] = ((const f32x4*)Vt)[((size_t)(bg * 8 + w) * 64 + l) * 4 + m];
    sacc[m] = (f32x4){0.f, 0.f, 0.f, 0.f};
  }

  build_xs(X, bg, i0, t, xs);
  __syncthreads();

  const short8* wp = (const short8*)Wb +
      ((size_t)iblk * PAIRS) * 2048 + w * 256 + l;
  const unsigned zm = (l < 32) ? 0xFFFFFFFFu : 0u;   // k<16 lanes mask

  short8 an[4];
  uint4 xn = ld_x_pair(xs, 0, l);
#pragma unroll
  for (int m = 0; m < 4; ++m) an[m] = wp[m * 64];
  wp += 2048;

  for (int pr = 0; pr < PAIRS; ++pr) {
    short8 ac[4];
#pragma unroll
    for (int m = 0; m < 4; ++m) ac[m] = an[m];
    uint4 xc = xn;
    if (pr + 1 < PAIRS) {                    // prefetch rides toward barrier
      xn = ld_x_pair(xs, pr + 1, l);
#pragma unroll
      for (int m = 0; m < 4; ++m) an[m] = wp[m * 64];
      wp += 2048;
    }
    // split the pair: x0 = even-i half (k<16), x1 = odd-i half (k>=16)
    uint4 x0u, x1u;
    x0u.x = xc.x & zm; x0u.y = xc.y & zm; x0u.z = xc.z & zm; x0u.w = xc.w & zm;
    x1u.x = xc.x ^ x0u.x; x1u.y = xc.y ^ x0u.y;
    x1u.z = xc.z ^ x0u.z; x1u.w = xc.w ^ x0u.w;
    const short8 x0 = u4s8(x0u), x1 = u4s8(x1u);

    const f32x4 z = {0.f, 0.f, 0.f, 0.f};
    f32x4 d0[4], d1[4];
#pragma unroll
    for (int m = 0; m < 4; ++m)
      d0[m] = __builtin_amdgcn_mfma_f32_16x16x32_bf16(ac[m], x0, z, 0, 0, 0);
#pragma unroll
    for (int m = 0; m < 4; ++m)
      d1[m] = __builtin_amdgcn_mfma_f32_16x16x32_bf16(ac[m], x1, z, 0, 0, 0);
    // d[m][r] = U[o=w*4+m][h=q*4+r][b=bl]

    float e0[4], e1[4];
#pragma unroll
    for (int m = 0; m < 4; ++m) {
      f32x4 pm = d0[m] * v[m];
      float p = (pm[0] + pm[1]) + (pm[2] + pm[3]);
      p = swz16_add(p);
      p += __shfl_xor(p, 32);
      e0[m] = EXP2(p);                       // v was pre-scaled by log2e
    }
#pragma unroll
    for (int m = 0; m < 4; ++m) {
      f32x4 pm = d1[m] * v[m];
      float p = (pm[0] + pm[1]) + (pm[2] + pm[3]);
      p = swz16_add(p);
      p += __shfl_xor(p, 32);
      e1[m] = EXP2(p);
    }
    const int s0 = (pr & 1) * 2;             // part slot pair for this pr
    if (q == 0) {
      part[s0][bl][w] = (e0[0] + e0[1]) + (e0[2] + e0[3]);
      part[s0 + 1][bl][w] = (e1[0] + e1[1]) + (e1[2] + e1[3]);
    }
    __syncthreads();                         // one barrier per i-PAIR
    const f32x4* pd0 = (const f32x4*)&part[s0][bl][0];
    const f32x4* pd1 = (const f32x4*)&part[s0 + 1][bl][0];
    f32x4 u0 = pd0[0] + pd0[1];
    f32x4 u1 = pd1[0] + pd1[1];
    const float den0 = (u0[0] + u0[1]) + (u0[2] + u0[3]);
    const float den1 = (u1[0] + u1[1]) + (u1[2] + u1[3]);
    const float r0 = __builtin_amdgcn_rcpf(den0);
    const float r1 = __builtin_amdgcn_rcpf(den1);
#pragma unroll
    for (int m = 0; m < 4; ++m) {
      sacc[m] += d0[m] * (e0[m] * r0);
      sacc[m] += d1[m] * (e1[m] * r1);
    }
    // slot pair s0 is rewritten two pairs later; the next pair's barrier
    // sits between this read and that write (WAR-safe).
  }

  float* pp = P + ((size_t)iblk * 128 + bg * 16 + bl) * 512 + w * 64 + q * 4;
#pragma unroll
  for (int m = 0; m < 4; ++m) *(f32x4*)(pp + m * 16) = sacc[m];
}

// ---- reduce over iblk + squash. MODE 0: V1p + Vt. 1: Vt = V1p+sq. 2: Out.
// Vt is written PRE-SCALED by log2e (consumed only by pass23's exp2 dot). --
template <int MODE>
__global__ __launch_bounds__(256)
void reduce_squash(const float* __restrict__ P, float* __restrict__ Vt,
                   float* __restrict__ V1p, float* __restrict__ Out) {
  __shared__ f32x4 red[8][32];
  const int t = threadIdx.x, qd = t & 31, kq = t >> 5;
  const int j4 = blockIdx.x * 32 + qd;             // quad index, 0..16383
  const f32x4* p = (const f32x4*)P + j4 + (size_t)kq * 8 * (SV_ELEMS / 4);
  f32x4 s = {0.f, 0.f, 0.f, 0.f};
#pragma unroll
  for (int k = 0; k < 8; ++k) s += p[(size_t)k * (SV_ELEMS / 4)];
  red[kq][qd] = s;
  __syncthreads();
  if (t < 32) {
    f32x4 a = red[0][t];
#pragma unroll
    for (int k2 = 1; k2 < 8; ++k2) a += red[k2][t];
    // norm over 16 h: 4 in-thread + quads j4^1, j4^2 (h-quarters)
    float ns = a[0] * a[0] + a[1] * a[1] + a[2] * a[2] + a[3] * a[3];
    ns += __shfl_xor(ns, 1);
    ns += __shfl_xor(ns, 2);
    const float sc = ns / ((1.f + ns) * sqrtf(ns));
    f32x4 vv = a * sc;
    if constexpr (MODE == 2) {
      ((f32x4*)Out)[j4] = vv;
    } else {
      if constexpr (MODE == 0) ((f32x4*)V1p)[j4] = vv;
      if constexpr (MODE == 1) vv += ((const f32x4*)V1p)[j4];
      const f32x4 vs = vv * LOG2E;                 // fold exp->exp2 scale
#pragma unroll
      for (int c = 0; c < 4; ++c) {
        const int j = j4 * 4 + c;
        const int b = j >> 9, oh = j & 511, o = oh >> 4, h = oh & 15;
        const int bg = b >> 4, bl = b & 15, w = o >> 2, m = o & 3, qq = h >> 2;
        Vt[(((size_t)(bg * 8 + w) * 64 + qq * 16 + bl) * 16) + m * 4 + (h & 3)] =
            vs[c];
      }
    }
  }
}

extern "C" void kernel_launch(void* const* d_in, const int* in_sizes, int n_in,
                              void* d_out, int out_size, void* d_ws, size_t ws_size,
                              hipStream_t stream) {
  const float* X  = (const float*)d_in[0];
  const float* Wg = (const float*)d_in[1];
  // d_in[2] = routing_iterations (3, hard-coded)

  float* P   = (float*)d_ws;                         // 64*65536 f = 16.8 MB
  float* Vt  = P + (size_t)NBLK_I * SV_ELEMS;        // 65536 f (frag order)
  float* V1p = Vt + SV_ELEMS;                        // 65536 f (plain)
  unsigned short* Wb = (unsigned short*)(V1p + SV_ELEMS);   // 18.9 MB packed
  float* out = (float*)d_out;                        // total ws ~36.3 MB

  conv_w<<<IN_CAPS / 2, 256, 0, stream>>>(Wg, Wb);   // 576 pair-blocks

  caps_pass1<<<512, 512, 0, stream>>>(Wb, X, P);
  reduce_squash<0><<<512, 256, 0, stream>>>(P, Vt, V1p, nullptr);

  caps_pass23<<<512, 512, 0, stream>>>(Wb, X, Vt, P);
  reduce_squash<1><<<512, 256, 0, stream>>>(P, Vt, V1p, nullptr);

  caps_pass23<<<512, 512, 0, stream>>>(Wb, X, Vt, P);
  reduce_squash<2><<<512, 256, 0, stream>>>(P, nullptr, nullptr, out);
}